// Round 1
// baseline (557.737 us; speedup 1.0000x reference)
//
#include <hip/hip_runtime.h>
#include <math.h>

// Problem constants: B=2, L=512, D=1024, H=16, DH=64
// N = B*L = 1024 rows, all matrices 1024x1024.

__device__ __forceinline__ float sigmoidf_(float z) { return 1.f / (1.f + expf(-z)); }

// ---------------------------------------------------------------------------
// Generic fp32 GEMM with bias: Out[M,N] = A[M,K] @ W[K,N] + bias[N]
// BM=BN=64, BK=16, 256 threads, 4x4 micro-tile per thread.
// ---------------------------------------------------------------------------
__global__ __launch_bounds__(256) void gemm_bias(const float* __restrict__ A,
                                                 const float* __restrict__ Wm,
                                                 const float* __restrict__ bias,
                                                 float* __restrict__ Out,
                                                 int M, int N, int K) {
    __shared__ float As[16][65];
    __shared__ float Bs[16][65];
    const int tid = threadIdx.x;
    const int tx = tid & 15, ty = tid >> 4;
    const int m0 = blockIdx.y * 64, n0 = blockIdx.x * 64;

    const int arow = tid >> 2;          // 0..63
    const int ac4  = (tid & 3) * 4;     // 0,4,8,12
    const int brow = tid >> 4;          // 0..15
    const int bc4  = (tid & 15) * 4;    // 0..60

    float acc[4][4] = {};

    for (int k0 = 0; k0 < K; k0 += 16) {
        float4 av = *reinterpret_cast<const float4*>(&A[(size_t)(m0 + arow) * K + k0 + ac4]);
        float4 bv = *reinterpret_cast<const float4*>(&Wm[(size_t)(k0 + brow) * N + n0 + bc4]);
        As[ac4 + 0][arow] = av.x;
        As[ac4 + 1][arow] = av.y;
        As[ac4 + 2][arow] = av.z;
        As[ac4 + 3][arow] = av.w;
        Bs[brow][bc4 + 0] = bv.x;
        Bs[brow][bc4 + 1] = bv.y;
        Bs[brow][bc4 + 2] = bv.z;
        Bs[brow][bc4 + 3] = bv.w;
        __syncthreads();
#pragma unroll
        for (int kk = 0; kk < 16; ++kk) {
            float ar[4], br[4];
#pragma unroll
            for (int i = 0; i < 4; ++i) ar[i] = As[kk][ty * 4 + i];
#pragma unroll
            for (int j = 0; j < 4; ++j) br[j] = Bs[kk][tx * 4 + j];
#pragma unroll
            for (int i = 0; i < 4; ++i)
#pragma unroll
                for (int j = 0; j < 4; ++j) acc[i][j] += ar[i] * br[j];
        }
        __syncthreads();
    }

#pragma unroll
    for (int i = 0; i < 4; ++i) {
        const int m = m0 + ty * 4 + i;
#pragma unroll
        for (int j = 0; j < 4; ++j) {
            const int n = n0 + tx * 4 + j;
            Out[(size_t)m * N + n] = acc[i][j] + bias[n];
        }
    }
}

// ---------------------------------------------------------------------------
// Gate scan: per (b,h), sequential over L in chunks of 64 with wave prefix-sum.
// Produces Gc[b,h,t] and a[b,h,t] = silu(K.sw_w+sw_b) / Gc.
// ---------------------------------------------------------------------------
__global__ __launch_bounds__(64) void scan_kernel(const float* __restrict__ x,
                                                  const float* __restrict__ Kb,
                                                  const float* __restrict__ gw_w,
                                                  const float* __restrict__ gw_b,
                                                  const float* __restrict__ sw_w,
                                                  const float* __restrict__ sw_b,
                                                  float* __restrict__ gc,
                                                  float* __restrict__ ab) {
    const int bh = blockIdx.x;       // 0..31
    const int b = bh >> 4, h = bh & 15;
    const int lane = threadIdx.x;    // 0..63

    __shared__ float gww[64], sww[64];
    gww[lane] = gw_w[lane];
    sww[lane] = sw_w[lane];
    __syncthreads();
    const float gwb = gw_b[0], swb = sw_b[0];

    float carry = 0.f;
    for (int c = 0; c < 8; ++c) {
        const int t = c * 64 + lane;
        const float* xr = x + (size_t)(b * 512 + t) * 1024 + h * 64;
        const float* kr = Kb + (size_t)(b * 512 + t) * 1024 + h * 64;
        float dg = 0.f, dk = 0.f;
#pragma unroll
        for (int d = 0; d < 64; d += 4) {
            float4 xv = *reinterpret_cast<const float4*>(xr + d);
            float4 kv = *reinterpret_cast<const float4*>(kr + d);
            dg += xv.x * gww[d] + xv.y * gww[d + 1] + xv.z * gww[d + 2] + xv.w * gww[d + 3];
            dk += kv.x * sww[d] + kv.y * sww[d + 1] + kv.z * sww[d + 2] + kv.w * sww[d + 3];
        }
        const float g = sigmoidf_(dg + gwb);
        float lg = logf(fmaxf(g, 1e-6f));
        // inclusive wave prefix sum of lg
        float ps = lg;
#pragma unroll
        for (int off = 1; off < 64; off <<= 1) {
            float v = __shfl_up(ps, off, 64);
            if (lane >= off) ps += v;
        }
        const float lsum = carry + ps;
        const float lclip = fminf(fmaxf(lsum, -30.f), 30.f);
        const float Gc = expf(lclip) + 1e-6f;
        const float z = dk + swb;
        const float R = z * sigmoidf_(z);  // silu
        gc[bh * 512 + t] = Gc;
        ab[bh * 512 + t] = R / Gc;
        carry += __shfl(ps, 63, 64);
    }
}

// ---------------------------------------------------------------------------
// Causal linear-attention tile kernel.
// MODE 0 (GLA):  Out=O1;  O1[r] = Gc[r] * sum_{tau<=r} (Q[r].K[tau]) * a[tau] * V[tau]
// MODE 1 (MA):   Out=Ytot; O2'[t'] = sum_{tau<=t'} (q2[t'].k2[tau]) * E[tau],
//                Ytot[t'+1] = O1[t'+1] + O2'[t'],  Ytot[0] = O1[0]
// grid = 32 (b,h) * 8 row-tiles = 256 blocks, 256 threads.
// ---------------------------------------------------------------------------
template <int MODE>
__global__ __launch_bounds__(256) void attn_kernel(const float* __restrict__ x,
                                                   const float* __restrict__ Qb,
                                                   const float* __restrict__ Kb,
                                                   const float* __restrict__ C2,
                                                   const float* O1,
                                                   const float* __restrict__ gc,
                                                   const float* __restrict__ ab,
                                                   float* __restrict__ Out) {
    const int bx = blockIdx.x;
    const int bh = bx >> 3, rt = bx & 7;
    const int b = bh >> 4, h = bh & 15;
    const int r0 = rt * 64;
    const int tid = threadIdx.x;
    const int r = tid & 63;      // row within tile (lane)
    const int eq = tid >> 6;     // wave index 0..3
    const int e0 = eq * 16;

    __shared__ float Qs[64][65];
    __shared__ float Ks[64][65];
    __shared__ float Vs[64][65];
    __shared__ float Ss[64][65];
    __shared__ float av[64];

    const size_t base = (size_t)(b * 512) * 1024 + h * 64;

    // stage Q tile (rows r0..r0+63)
    for (int idx = tid; idx < 1024; idx += 256) {
        const int rr = idx >> 4;
        const int c4 = (idx & 15) << 2;
        float4 qv = *reinterpret_cast<const float4*>(&Qb[base + (size_t)(r0 + rr) * 1024 + c4]);
        if (MODE == 1) {
            qv.x = (qv.x < 0.f ? qv.x : 0.02f * qv.x) * 0.125f;
            qv.y = (qv.y < 0.f ? qv.y : 0.02f * qv.y) * 0.125f;
            qv.z = (qv.z < 0.f ? qv.z : 0.02f * qv.z) * 0.125f;
            qv.w = (qv.w < 0.f ? qv.w : 0.02f * qv.w) * 0.125f;
        }
        Qs[rr][c4 + 0] = qv.x;
        Qs[rr][c4 + 1] = qv.y;
        Qs[rr][c4 + 2] = qv.z;
        Qs[rr][c4 + 3] = qv.w;
    }

    float acc[16] = {};

    for (int jt = 0; jt <= rt; ++jt) {
        const int c0 = jt * 64;
        __syncthreads();  // protect prev tile's LDS reads (and initial Q stage)
        for (int idx = tid; idx < 1024; idx += 256) {
            const int cc = idx >> 4;
            const int c4 = (idx & 15) << 2;
            const int tau = c0 + cc;
            float4 kv, vv;
            if (MODE == 0) {
                kv = *reinterpret_cast<const float4*>(&Kb[base + (size_t)tau * 1024 + c4]);
                vv = *reinterpret_cast<const float4*>(&x[base + (size_t)tau * 1024 + c4]);
            } else {
                if (tau <= 510) {
                    float4 cv = *reinterpret_cast<const float4*>(&C2[base + (size_t)tau * 1024 + c4]);
                    kv.x = sigmoidf_(cv.x * 6.25e-4f);
                    kv.y = sigmoidf_(cv.y * 6.25e-4f);
                    kv.z = sigmoidf_(cv.z * 6.25e-4f);
                    kv.w = sigmoidf_(cv.w * 6.25e-4f);
                    float4 xv = *reinterpret_cast<const float4*>(&x[base + (size_t)(tau + 1) * 1024 + c4]);
                    float4 ov = *reinterpret_cast<const float4*>(&O1[base + (size_t)tau * 1024 + c4]);
                    vv.x = xv.x - ov.x;
                    vv.y = xv.y - ov.y;
                    vv.z = xv.z - ov.z;
                    vv.w = xv.w - ov.w;
                } else {
                    kv.x = kv.y = kv.z = kv.w = 0.f;
                    vv.x = vv.y = vv.z = vv.w = 0.f;
                }
            }
            Ks[cc][c4 + 0] = kv.x; Ks[cc][c4 + 1] = kv.y; Ks[cc][c4 + 2] = kv.z; Ks[cc][c4 + 3] = kv.w;
            Vs[cc][c4 + 0] = vv.x; Vs[cc][c4 + 1] = vv.y; Vs[cc][c4 + 2] = vv.z; Vs[cc][c4 + 3] = vv.w;
        }
        if (MODE == 0 && tid < 64) av[tid] = ab[bh * 512 + c0 + tid];
        __syncthreads();

        // phase A: scores S[r][c] for c in [e0, e0+16)
        {
            float s[16] = {};
            for (int d = 0; d < 64; ++d) {
                const float qd = Qs[r][d];
#pragma unroll
                for (int cc = 0; cc < 16; ++cc) s[cc] += qd * Ks[e0 + cc][d];
            }
#pragma unroll
            for (int cc = 0; cc < 16; ++cc) {
                const int c = e0 + cc;
                float sv = s[cc];
                if (MODE == 0) sv *= av[c];
                if (c0 + c > r0 + r) sv = 0.f;  // causal (inclusive) mask
                Ss[r][c] = sv;
            }
        }
        __syncthreads();

        // phase B: acc[e] += S[r][c] * V[c][e]
        for (int c = 0; c < 64; ++c) {
            const float sv = Ss[r][c];
#pragma unroll
            for (int ee = 0; ee < 16; ++ee) acc[ee] += sv * Vs[c][e0 + ee];
        }
    }

    if (MODE == 0) {
        const float gcr = gc[bh * 512 + r0 + r];
#pragma unroll
        for (int ee = 0; ee < 16; ++ee)
            Out[base + (size_t)(r0 + r) * 1024 + e0 + ee] = acc[ee] * gcr;
    } else {
        const int tp = r0 + r;  // t'
        if (tp <= 510) {
#pragma unroll
            for (int ee = 0; ee < 16; ++ee)
                Out[base + (size_t)(tp + 1) * 1024 + e0 + ee] =
                    O1[base + (size_t)(tp + 1) * 1024 + e0 + ee] + acc[ee];
        }
        if (rt == 0 && r == 0) {
#pragma unroll
            for (int ee = 0; ee < 16; ++ee)
                Out[base + e0 + ee] = O1[base + e0 + ee];
        }
    }
}

// ---------------------------------------------------------------------------
extern "C" void kernel_launch(void* const* d_in, const int* in_sizes, int n_in,
                              void* d_out, int out_size, void* d_ws, size_t ws_size,
                              hipStream_t stream) {
    const float* x   = (const float*)d_in[0];
    const float* q1w = (const float*)d_in[1];
    const float* q1b = (const float*)d_in[2];
    const float* k1w = (const float*)d_in[3];
    const float* k1b = (const float*)d_in[4];
    const float* k2w = (const float*)d_in[5];
    const float* k2b = (const float*)d_in[6];
    const float* gww = (const float*)d_in[7];
    const float* gwb = (const float*)d_in[8];
    const float* sww = (const float*)d_in[9];
    const float* swb = (const float*)d_in[10];
    const float* cpw = (const float*)d_in[11];
    const float* cpb = (const float*)d_in[12];
    float* out = (float*)d_out;

    float* ws = (float*)d_ws;
    float* Q   = ws;                       // 1M floats
    float* K   = ws + 1048576;             // 1M
    float* C2  = ws + 2097152;             // 1M
    float* O1  = ws + 3145728;             // 1M
    float* Yt  = ws + 4194304;             // 1M
    float* gcb = ws + 5242880;             // 16K
    float* abb = ws + 5242880 + 16384;     // 16K
    // total: 5,275,648 floats = 21.1 MB of d_ws

    const dim3 g16(16, 16);
    gemm_bias<<<g16, 256, 0, stream>>>(x, q1w, q1b, Q, 1024, 1024, 1024);
    gemm_bias<<<g16, 256, 0, stream>>>(x, k1w, k1b, K, 1024, 1024, 1024);
    gemm_bias<<<g16, 256, 0, stream>>>(x, k2w, k2b, C2, 1024, 1024, 1024);
    scan_kernel<<<32, 64, 0, stream>>>(x, K, gww, gwb, sww, swb, gcb, abb);
    attn_kernel<0><<<256, 256, 0, stream>>>(x, Q, K, C2, O1, gcb, abb, O1);
    attn_kernel<1><<<256, 256, 0, stream>>>(x, Q, K, C2, O1, gcb, abb, Yt);
    gemm_bias<<<g16, 256, 0, stream>>>(Yt, cpw, cpb, out, 1024, 1024, 1024);
}